// Round 8
// baseline (635.308 us; speedup 1.0000x reference)
//
#include <hip/hip_runtime.h>
#include <math.h>

typedef unsigned short u16;
typedef __attribute__((ext_vector_type(8))) short short8;   // 8 x bf16 (4 VGPRs)
typedef __attribute__((ext_vector_type(4))) short short4b;  // 4 x bf16 (2 VGPRs)
typedef __attribute__((ext_vector_type(4))) float f32x4;

#define MFMA(a,b,c) __builtin_amdgcn_mfma_f32_16x16x32_bf16(a, b, c, 0, 0, 0)
// XOR-swizzled u16 offset of 16B chunk `ch` in row `row` (stride 64 u16)
#define SWZ(row, ch) ((((ch) ^ ((row) & 7)) << 3))
#define EXP2F(x) __builtin_amdgcn_exp2f(x)

// 16x16x16 bf16 MFMA (K=16): A-frag = 4 bf16, row=l&15, k=(l>>4)*4+j.
static __device__ __forceinline__ f32x4 MFMA16(short4b a, short4b b, f32x4 c) {
#if __has_builtin(__builtin_amdgcn_mfma_f32_16x16x16bf16_1k)
    return __builtin_amdgcn_mfma_f32_16x16x16bf16_1k(a, b, c, 0, 0, 0);
#else
    f32x4 d;
    asm volatile("v_mfma_f32_16x16x16_bf16 %0, %1, %2, %3\n\ts_nop 7"
                 : "=v"(d) : "v"(a), "v"(b), "v"(c));
    return d;
#endif
}

// Async global->LDS, 16B per lane. LDS dest is wave-uniform base + lane*16.
__device__ __forceinline__ void gload_lds16(const u16* g, u16* l) {
    __builtin_amdgcn_global_load_lds(
        (const __attribute__((address_space(1))) unsigned int*)(const void*)g,
        (__attribute__((address_space(3))) unsigned int*)(void*)l, 16, 0, 0);
}

__device__ __forceinline__ float b2f(u16 v) {
    union { unsigned int i; float f; } c; c.i = ((unsigned int)v) << 16; return c.f;
}
__device__ __forceinline__ u16 f2b(float f) {   // RNE f32->bf16 (finite inputs only)
    union { float f; unsigned int i; } c; c.f = f;
    unsigned int u = c.i;
    return (u16)((u + 0x7fffu + ((u >> 16) & 1u)) >> 16);
}
__device__ __forceinline__ u16 f2b_p(float f) { // round-half-up, positive finite
    union { float f; unsigned int i; } c; c.f = f;
    return (u16)((c.i + 0x8000u) >> 16);
}

// Fast exact-GELU: erf via Abramowitz-Stegun 7.1.26 (|eps| <= 1.5e-7).
__device__ __forceinline__ float gelu_fast(float v) {
    float az = fabsf(v) * 0.70710678118f;               // |v|/sqrt(2)
    float t  = __builtin_amdgcn_rcpf(1.0f + 0.3275911f * az);
    float poly = ((((1.061405429f * t - 1.453152027f) * t + 1.421413741f) * t
                   - 0.284496736f) * t + 0.254829592f) * t;
    float e = EXP2F(az * az * -1.4426950408889634f);    // exp(-az^2)
    float erfv = 1.0f - poly * e;
    erfv = v >= 0.f ? erfv : -erfv;                     // erf is odd
    return 0.5f * v * (1.0f + erfv);
}

// ---------------------------------------------------------------------------
// Batched weight transpose: src [K][N] f32 -> dst [N][K] bf16 (K-innermost)
// ---------------------------------------------------------------------------
struct TWArgs { const float* src[8]; u16* dst[8]; int K[8]; int N[8]; };

__global__ __launch_bounds__(256) void transpose_w(TWArgs a) {
    int wi = blockIdx.z;
    int K = a.K[wi], N = a.N[wi];
    int n0 = blockIdx.x * 32, k0 = blockIdx.y * 32;
    if (n0 >= N || k0 >= K) return;
    __shared__ float t[32][33];
    const float* s = a.src[wi]; u16* d = a.dst[wi];
    int tx = threadIdx.x & 31, ty = threadIdx.x >> 5;   // 32 x 8
    for (int i = 0; i < 32; i += 8)
        t[ty + i][tx] = s[(size_t)(k0 + ty + i) * N + n0 + tx];
    __syncthreads();
    for (int i = 0; i < 32; i += 8)
        d[(size_t)(n0 + ty + i) * K + k0 + tx] = f2b(t[tx][ty + i]);
}

// ---------------------------------------------------------------------------
// LN over channel dim with transpose: x f32 [B,384,1024] -> xn bf16 [R,384]
// ---------------------------------------------------------------------------
__global__ __launch_bounds__(256)
void ln_tr(const float* __restrict__ x0, const float* __restrict__ x1,
           const float* __restrict__ w0, const float* __restrict__ bb0,
           const float* __restrict__ w1, const float* __restrict__ bb1,
           u16* __restrict__ xn0, u16* __restrict__ xn1) {
    int br = blockIdx.z;
    const float* x  = br ? x1 : x0;
    const float* wv = br ? w1 : w0;
    const float* bv = br ? bb1 : bb0;
    u16* xn = br ? xn1 : xn0;
    int b = blockIdx.y, n0 = blockIdx.x * 32;
    __shared__ float tile[32][385];
    __shared__ float smu[32], srs[32];
    int tid = threadIdx.x;
    const float* xb = x + (size_t)b * 384 * 1024 + n0;
    for (int idx = tid; idx < 384 * 8; idx += 256) {
        int c = idx >> 3, q = idx & 7;
        const float4 v = *(const float4*)&xb[(size_t)c * 1024 + q * 4];
        tile[q * 4 + 0][c] = v.x; tile[q * 4 + 1][c] = v.y;
        tile[q * 4 + 2][c] = v.z; tile[q * 4 + 3][c] = v.w;
    }
    __syncthreads();
    {
        int nn = tid >> 3, part = tid & 7;
        float s1 = 0.f, s2 = 0.f;
        for (int c = part * 48; c < part * 48 + 48; ++c) {
            float v = tile[nn][c]; s1 += v; s2 += v * v;
        }
        for (int off = 1; off < 8; off <<= 1) {
            s1 += __shfl_xor(s1, off, 64); s2 += __shfl_xor(s2, off, 64);
        }
        if (part == 0) {
            float mu = s1 * (1.f / 384.f);
            float var = s2 * (1.f / 384.f) - mu * mu;
            smu[nn] = mu; srs[nn] = rsqrtf(fmaxf(var, 0.f) + 1e-5f);
        }
    }
    __syncthreads();
    size_t rowbase = (size_t)b * 1024 + n0;
    for (int idx = tid; idx < 1536; idx += 256) {
        int nn = idx / 48, c0 = (idx - nn * 48) * 8;
        float mu = smu[nn], rs = srs[nn];
        u16 ov[8];
        #pragma unroll
        for (int k = 0; k < 8; k++) {
            int c = c0 + k;
            ov[k] = f2b((tile[nn][c] - mu) * rs * wv[c] + bv[c]);
        }
        *(uint4*)&xn[(rowbase + nn) * 384 + c0] = *(uint4*)ov;
    }
}

// ---------------------------------------------------------------------------
// Row LayerNorm: in f32 [R,384] -> out bf16 [R,384]; one wave per row
// ---------------------------------------------------------------------------
__global__ __launch_bounds__(256)
void ln_rows(const float* __restrict__ i0, const float* __restrict__ i1,
             const float* __restrict__ w0, const float* __restrict__ bb0,
             const float* __restrict__ w1, const float* __restrict__ bb1,
             u16* __restrict__ o0, u16* __restrict__ o1) {
    int br = blockIdx.z;
    const float* in = br ? i1 : i0;
    const float* wv = br ? w1 : w0;
    const float* bv = br ? bb1 : bb0;
    u16* out = br ? o1 : o0;
    int w = threadIdx.x >> 6, l = threadIdx.x & 63;
    size_t row = (size_t)blockIdx.x * 4 + w;
    const float* p = in + row * 384;
    float v[6]; float s1 = 0.f, s2 = 0.f;
    #pragma unroll
    for (int j = 0; j < 6; j++) { v[j] = p[j * 64 + l]; s1 += v[j]; s2 += v[j] * v[j]; }
    for (int off = 1; off < 64; off <<= 1) {
        s1 += __shfl_xor(s1, off, 64); s2 += __shfl_xor(s2, off, 64);
    }
    float mu = s1 * (1.f / 384.f);
    float var = s2 * (1.f / 384.f) - mu * mu;
    float rs = rsqrtf(fmaxf(var, 0.f) + 1e-5f);
    #pragma unroll
    for (int j = 0; j < 6; j++) {
        int c = j * 64 + l;
        out[row * 384 + c] = f2b((v[j] - mu) * rs * wv[c] + bv[c]);
    }
}

// ---------------------------------------------------------------------------
// GEMM: C[M,N] = A[M,K] (row-major bf16) x Bt[N,K] (row-major bf16)
// m97 structure — global_load_lds width=16 staging, linear LDS, double
// buffer, one barrier/K-step. 4 waves (2x2). BNT = column-tile width:
//   BNT=128: grid.x = N/128, wave tile 64x64  (4x4 frags)
//   BNT=64 : grid.x = N/64,  wave tile 64x32  (4x2 frags) — used for the
//            N=384 MLP fc2 GEMMs so grid = 768 blocks = 3.0/CU balanced
//            (was (3,64,2)=384 = 1.5/CU: half the CUs ran 2 serial rounds).
// EPI: 0 = kqv epilogue, 1 = f32 +bias+x-residual, 2 = bf16 gelu_fast,
//      3 = f32 +bias+residual.
// ---------------------------------------------------------------------------
template <int EPI, int BNT>
__global__ __launch_bounds__(256)
void gemm128(const u16* __restrict__ A0, const u16* __restrict__ A1,
             const u16* __restrict__ B0, const u16* __restrict__ B1,
             void* C0v, void* C1v,
             const float* __restrict__ bias0, const float* __restrict__ bias1,
             const void* R0v, const void* R1v,
             int N, int K) {
    const int br = blockIdx.z;
    const u16* A = br ? A1 : A0;
    const u16* B = br ? B1 : B0;
    void* Cv = br ? C1v : C0v;
    const float* bias = br ? bias1 : bias0;
    const void* Rv = br ? R1v : R0v;

    const int n0 = blockIdx.x * BNT;
    const int m0 = blockIdx.y * 128;
    const int tid = threadIdx.x;
    const int w = tid >> 6, l = tid & 63;
    const int wm = w >> 1, wn = w & 1;
    const int lr = l & 15, lq = l >> 4;
    constexpr int NT = BNT / 32;          // n-frags per wave

    __shared__ alignas(16) u16 As[2][128 * 32];
    __shared__ alignas(16) u16 Bs[2][BNT * 32];

    f32x4 acc[4][NT];
    #pragma unroll
    for (int i = 0; i < 4; i++)
        #pragma unroll
        for (int j = 0; j < NT; j++) acc[i][j] = (f32x4)0.0f;

    // A staging: 512 chunks, 2 per thread. chunk idx = w*128 + i*64 + l
    const int idx0 = w * 128 + l;
    const int row0 = idx0 >> 2, ch0 = (idx0 & 3) * 8;
    const int idx1 = idx0 + 64;
    const int row1 = idx1 >> 2, ch1 = (idx1 & 3) * 8;
    const u16* Asrc0 = A + (size_t)(m0 + row0) * K + ch0;
    const u16* Asrc1 = A + (size_t)(m0 + row1) * K + ch1;
    const int ldsoff0 = (w * 2 + 0) * 512, ldsoff1 = (w * 2 + 1) * 512;
    // B staging: BNT*4 chunks (2/thread at 128, 1/thread at 64)
    const u16* Bsrc0;
    const u16* Bsrc1 = nullptr;
    int bldsoff0, bldsoff1 = 0;
    if constexpr (BNT == 128) {
        Bsrc0 = B + (size_t)(n0 + row0) * K + ch0;
        Bsrc1 = B + (size_t)(n0 + row1) * K + ch1;
        bldsoff0 = ldsoff0; bldsoff1 = ldsoff1;
    } else {
        Bsrc0 = B + (size_t)(n0 + (tid >> 2)) * K + (tid & 3) * 8;
        bldsoff0 = w * 512;
    }

    const int nk = K >> 5;
    // stage kt=0 into buf 0
    gload_lds16(Asrc0, &As[0][ldsoff0]);
    gload_lds16(Asrc1, &As[0][ldsoff1]);
    gload_lds16(Bsrc0, &Bs[0][bldsoff0]);
    if constexpr (BNT == 128) gload_lds16(Bsrc1, &Bs[0][bldsoff1]);
    __syncthreads();

    for (int kt = 0; kt < nk; ++kt) {
        const int cur = kt & 1;
        if (kt + 1 < nk) {      // async-stage kt+1 into the other buffer
            const int nx = cur ^ 1;
            const int kb = (kt + 1) * 32;
            gload_lds16(Asrc0 + kb, &As[nx][ldsoff0]);
            gload_lds16(Asrc1 + kb, &As[nx][ldsoff1]);
            gload_lds16(Bsrc0 + kb, &Bs[nx][bldsoff0]);
            if constexpr (BNT == 128) gload_lds16(Bsrc1 + kb, &Bs[nx][bldsoff1]);
        }
        short8 af[4], bf[NT];
        #pragma unroll
        for (int mt = 0; mt < 4; ++mt)
            af[mt] = *(const short8*)&As[cur][(wm * 64 + mt * 16 + lr) * 32 + lq * 8];
        #pragma unroll
        for (int nt = 0; nt < NT; ++nt)
            bf[nt] = *(const short8*)&Bs[cur][(wn * (BNT / 2) + nt * 16 + lr) * 32 + lq * 8];
        #pragma unroll
        for (int mt = 0; mt < 4; ++mt)
            #pragma unroll
            for (int nt = 0; nt < NT; ++nt)
                acc[mt][nt] = MFMA(af[mt], bf[nt], acc[mt][nt]);
        __syncthreads();    // drains vmcnt: buf nx ready, buf cur reusable
    }

    #pragma unroll
    for (int mt = 0; mt < 4; ++mt)
        #pragma unroll
        for (int nt = 0; nt < NT; ++nt) {
            const int col = n0 + wn * (BNT / 2) + nt * 16 + lr;
            const int rbase = m0 + wm * 64 + mt * 16 + lq * 4;
            const float bv = (EPI == 0) ? 0.f : bias[col];
            #pragma unroll
            for (int r = 0; r < 4; r++) {
                const int row = rbase + r;
                const size_t idx = (size_t)row * N + col;
                float v = acc[mt][nt][r];
                if (EPI == 0) {
                    if (col < 768) {
                        // q pre-scaled by 0.125*log2(e) for exp2-softmax
                        ((u16*)Cv)[idx] = f2b(col >= 384 ? v * 0.18033688f : v);
                    } else {    // V -> transposed vt[b][h][hd][n]
                        u16* vtb = (u16*)Rv;
                        vtb[((((size_t)(row >> 10)) * 6 + ((col - 768) >> 6)) * 64
                             + (col & 63)) * 1024 + (row & 1023)] = f2b(v);
                    }
                } else if (EPI == 1) {
                    float xr = ((const float*)Rv)[
                        ((size_t)(row >> 10) * 384 + col) * 1024 + (row & 1023)];
                    ((float*)Cv)[idx] = v + bv + xr;
                } else if (EPI == 2) {
                    ((u16*)Cv)[idx] = f2b(gelu_fast(v + bv));
                } else {
                    ((float*)Cv)[idx] = v + bv + ((const float*)Rv)[idx];
                }
            }
        }
}

// ---------------------------------------------------------------------------
// Cross flash-attention v6 (round-3 version — best measured, 139 us).
// ---------------------------------------------------------------------------
__global__ __launch_bounds__(256)
void attn_k(const u16* __restrict__ kqvA, const u16* __restrict__ kqvB,
            const u16* __restrict__ vtA, const u16* __restrict__ vtB,
            u16* __restrict__ oA, u16* __restrict__ oB) {
    const int bid = blockIdx.x;
    const int g = bid & 7, qb = (bid >> 3) & 7, s = bid >> 6;
    const int grp = s * 8 + g;                  // 0..191
    const int ob = grp & 1, h = (grp >> 1) % 6, b = grp / 12;

    const u16* kqvQ  = (ob ? kqvB : kqvA) + (size_t)b * 1024 * 1152;
    const u16* kqvKV = (ob ? kqvA : kqvB) + (size_t)b * 1024 * 1152;
    const u16* vt    = (ob ? vtA : vtB) + ((size_t)b * 6 + h) * 64 * 1024;
    u16* outp = (ob ? oB : oA) + (size_t)b * 1024 * 384;
    const u16* qp = kqvQ + 384 + h * 64;
    const u16* kp = kqvKV + h * 64;

    __shared__ alignas(16) u16 Ks[2][64 * 64];
    __shared__ alignas(16) u16 Vts[2][64 * 64];   // V^T tile: [d][k]

    const int tid = threadIdx.x, w = tid >> 6, l = tid & 63;
    const int lr = l & 15, lq = l >> 4;

    // Q fragments in registers (loop-invariant, 16 VGPRs).
    short8 qf[2][2];
    #pragma unroll
    for (int a = 0; a < 2; a++)
        #pragma unroll
        for (int ks = 0; ks < 2; ks++)
            qf[a][ks] = *(const short8*)&qp[
                (size_t)(qb * 128 + w * 32 + a * 16 + lr) * 1152 + ks * 32 + lq * 8];

    const int srow = tid >> 3, sch = tid & 7;
    uint4 kpre[2][2], vpre[2][2];               // slot parity == tile parity
    #pragma unroll
    for (int t = 0; t < 2; t++)
        #pragma unroll
        for (int i = 0; i < 2; i++) {
            int row = srow + i * 32;
            kpre[t][i] = *(const uint4*)&kp[(size_t)(t * 64 + row) * 1152 + sch * 8];
            vpre[t][i] = *(const uint4*)&vt[(size_t)row * 1024 + t * 64 + sch * 8];
        }

    // prologue: stage tile 0 into buf 0; refill slot 0 <- tile 2
    #pragma unroll
    for (int i = 0; i < 2; i++) {
        int row = srow + i * 32;
        int o = row * 64 + SWZ(row, sch);
        *(uint4*)&Ks[0][o] = kpre[0][i];
        *(uint4*)&Vts[0][o] = vpre[0][i];
    }
    #pragma unroll
    for (int i = 0; i < 2; i++) {
        int row = srow + i * 32;
        kpre[0][i] = *(const uint4*)&kp[(size_t)(2 * 64 + row) * 1152 + sch * 8];
        vpre[0][i] = *(const uint4*)&vt[(size_t)row * 1024 + 2 * 64 + sch * 8];
    }

    f32x4 oacc[2][4];
    float psum[2] = {0.f, 0.f};
    #pragma unroll
    for (int a = 0; a < 2; a++)
        #pragma unroll
        for (int n = 0; n < 4; n++) oacc[a][n] = (f32x4)0.0f;

    __syncthreads();

    for (int jt = 0; jt < 16; ++jt) {
        const int cur = jt & 1, nx = cur ^ 1;
        if (jt + 1 < 16) {
            #pragma unroll
            for (int i = 0; i < 2; i++) {
                int row = srow + i * 32;
                int o = row * 64 + SWZ(row, sch);
                *(uint4*)&Ks[nx][o] = kpre[nx][i];
                *(uint4*)&Vts[nx][o] = vpre[nx][i];
            }
            if (jt + 3 < 16) {
                #pragma unroll
                for (int i = 0; i < 2; i++) {
                    int row = srow + i * 32;
                    kpre[nx][i] = *(const uint4*)&kp[(size_t)((jt + 3) * 64 + row) * 1152 + sch * 8];
                    vpre[nx][i] = *(const uint4*)&vt[(size_t)row * 1024 + (jt + 3) * 64 + sch * 8];
                }
            }
        }

        // S^T = K Q^T : sacc[kb][a], lane holds q=l&15 (col), k=kb*16+lq*4+r
        f32x4 sacc[4][2];
        #pragma unroll
        for (int kb = 0; kb < 4; kb++)
            #pragma unroll
            for (int a = 0; a < 2; a++) sacc[kb][a] = (f32x4)0.0f;
        __builtin_amdgcn_s_setprio(1);
        #pragma unroll
        for (int ks = 0; ks < 2; ++ks) {
            short8 bk[4];
            #pragma unroll
            for (int kb = 0; kb < 4; kb++) {
                int row = kb * 16 + lr;
                bk[kb] = *(const short8*)&Ks[cur][row * 64 + SWZ(row, ks * 4 + lq)];
            }
            #pragma unroll
            for (int kb = 0; kb < 4; kb++)
                #pragma unroll
                for (int a = 0; a < 2; a++)
                    sacc[kb][a] = MFMA(bk[kb], qf[a][ks], sacc[kb][a]);
        }
        __builtin_amdgcn_s_setprio(0);

        // P = exp2(S^T) entirely in registers: pack into 16x16x16 A-frags
        short4b ap16[2][4];
        #pragma unroll
        for (int a = 0; a < 2; a++)
            #pragma unroll
            for (int kb = 0; kb < 4; kb++) {
                f32x4 s4 = sacc[kb][a];
                float p0 = EXP2F(s4[0]), p1 = EXP2F(s4[1]);
                float p2 = EXP2F(s4[2]), p3 = EXP2F(s4[3]);
                psum[a] += (p0 + p1) + (p2 + p3);
                short4b pk;
                pk[0] = (short)f2b_p(p0); pk[1] = (short)f2b_p(p1);
                pk[2] = (short)f2b_p(p2); pk[3] = (short)f2b_p(p3);
                ap16[a][kb] = pk;
            }

        // O += P x V : PV via 16x16x16, B-frag = V^T[d = n*16+lr][k 4-contig]
        __builtin_amdgcn_s_setprio(1);
        #pragma unroll
        for (int kb = 0; kb < 4; ++kb) {
            short4b bv16[4];
            #pragma unroll
            for (int n = 0; n < 4; n++) {
                int row = n * 16 + lr;
                int addr = row * 64 + SWZ(row, kb * 2 + (lq >> 1)) + (lq & 1) * 4;
                bv16[n] = *(const short4b*)&Vts[cur][addr];
            }
            #pragma unroll
            for (int a = 0; a < 2; a++)
                #pragma unroll
                for (int n = 0; n < 4; n++)
                    oacc[a][n] = MFMA16(ap16[a][kb], bv16[n], oacc[a][n]);
        }
        __builtin_amdgcn_s_setprio(0);
        __syncthreads();   // tile jt+1 staged AND buf cur free for tile jt+2
    }

    #pragma unroll
    for (int a = 0; a < 2; a++) {
        psum[a] += __shfl_xor(psum[a], 16, 64);
        psum[a] += __shfl_xor(psum[a], 32, 64);
        psum[a] = 1.f / psum[a];
    }
    float rec[2][4];
    #pragma unroll
    for (int a = 0; a < 2; a++)
        #pragma unroll
        for (int r = 0; r < 4; r++)
            rec[a][r] = __shfl(psum[a], lq * 4 + r, 64);

    #pragma unroll
    for (int a = 0; a < 2; a++)
        #pragma unroll
        for (int n = 0; n < 4; n++)
            #pragma unroll
            for (int r = 0; r < 4; r++) {
                size_t row = (size_t)qb * 128 + w * 32 + a * 16 + lq * 4 + r;
                int col = h * 64 + n * 16 + lr;
                outp[row * 384 + col] = f2b(oacc[a][n][r] * rec[a][r]);
            }
}

// ---------------------------------------------------------------------------
// Final transpose: res f32 [R,384] -> d_out FLOAT32 [2][16][384][1024]
// ---------------------------------------------------------------------------
__global__ __launch_bounds__(256)
void transpose_out(const float* __restrict__ r0, const float* __restrict__ r1,
                   float* __restrict__ out) {
    int z = blockIdx.z, ob = z >> 4, b = z & 15;
    const float* rp = ob ? r1 : r0;
    int c0 = blockIdx.y * 32, n0 = blockIdx.x * 32;
    __shared__ float t[32][33];
    int tx = threadIdx.x & 31, ty = threadIdx.x >> 5;
    for (int i = 0; i < 32; i += 8)
        t[ty + i][tx] = rp[((size_t)b * 1024 + n0 + ty + i) * 384 + c0 + tx];
    __syncthreads();
    for (int i = 0; i < 32; i += 8)
        out[(size_t)ob * 6291456 + ((size_t)b * 384 + c0 + ty + i) * 1024 + n0 + tx]
            = t[tx][ty + i];
}

// ---------------------------------------------------------------------------
extern "C" void kernel_launch(void* const* d_in, const int* in_sizes, int n_in,
                              void* d_out, int out_size, void* d_ws, size_t ws_size,
                              hipStream_t stream) {
    const float* x1      = (const float*)d_in[0];
    const float* x2      = (const float*)d_in[1];
    const float* ln_a1_w = (const float*)d_in[2];
    const float* ln_a1_b = (const float*)d_in[3];
    const float* kqv1_w  = (const float*)d_in[4];
    const float* ln_a2_w = (const float*)d_in[5];
    const float* ln_a2_b = (const float*)d_in[6];
    const float* kqv2_w  = (const float*)d_in[7];
    const float* proj1_w = (const float*)d_in[8];
    const float* proj1_b = (const float*)d_in[9];
    const float* proj2_w = (const float*)d_in[10];
    const float* proj2_b = (const float*)d_in[11];
    const float* ln1_w   = (const float*)d_in[12];
    const float* ln1_b   = (const float*)d_in[13];
    const float* ln2_w   = (const float*)d_in[14];
    const float* ln2_b   = (const float*)d_in[15];
    const float* m1f1w   = (const float*)d_in[16];
    const float* m1f1b   = (const float*)d_in[17];
    const float* m1f2w   = (const float*)d_in[18];
    const float* m1f2b   = (const float*)d_in[19];
    const float* m2f1w   = (const float*)d_in[20];
    const float* m2f1b   = (const float*)d_in[21];
    const float* m2f2w   = (const float*)d_in[22];
    const float* m2f2b   = (const float*)d_in[23];
    (void)in_sizes; (void)n_in; (void)out_size; (void)ws_size;

    const size_t R = 16384;
    char* ws = (char*)d_ws;
    size_t off = 0;
    auto alloc = [&](size_t bytes) -> char* {
        char* p = ws + off;
        off = (off + bytes + 255) & ~(size_t)255;
        return p;
    };
    // --- weights (persistent, 7.08 MB) ---
    u16* kqv1t  = (u16*)alloc(1152 * 384 * 2);
    u16* kqv2t  = (u16*)alloc(1152 * 384 * 2);
    u16* proj1t = (u16*)alloc(384 * 384 * 2);
    u16* proj2t = (u16*)alloc(384 * 384 * 2);
    u16* fc11t  = (u16*)alloc(1536 * 384 * 2);
    u16* fc12t  = (u16*)alloc(1536 * 384 * 2);
    u16* fc21t  = (u16*)alloc(384 * 1536 * 2);
    u16* fc22t  = (u16*)alloc(384 * 1536 * 2);
    // --- REGION_B: xn (bf16 [R,384] x2), later h ---
    u16* xn1 = (u16*)alloc(R * 384 * 2);
    u16* xn2 = (u16*)alloc(R * 384 * 2);
    // --- REGION_C: kqv (bf16 [R,1152] x2); later oa (f32 x2) + hid_b2 ---
    char* regC = alloc(R * 1152 * 2 * 2);
    u16* kqv1 = (u16*)regC;
    u16* kqv2 = (u16*)(regC + R * 1152 * 2);
    float* oa1 = (float*)regC;
    float* oa2 = (float*)(regC + R * 384 * 4);
    u16* hid_b2 = (u16*)(regC + 2 * R * 384 * 4);
    // d_out (50.33 MB) scratch: at (25.17) + vt1/vt2 (12.58 each); exact fit
    u16* at1 = (u16*)d_out;
    u16* at2 = at1 + R * 384;
    u16* vt1 = at2 + R * 384;                   // [16][6][64][1024] bf16
    u16* vt2 = vt1 + (size_t)16 * 6 * 64 * 1024;
    u16* hid_b1 = (u16*)d_out;                  // later: bf16 [R/2,1536]

    // 1) weight transposes
    TWArgs tw;
    tw.src[0] = kqv1_w;  tw.dst[0] = kqv1t;  tw.K[0] = 384;  tw.N[0] = 1152;
    tw.src[1] = kqv2_w;  tw.dst[1] = kqv2t;  tw.K[1] = 384;  tw.N[1] = 1152;
    tw.src[2] = proj1_w; tw.dst[2] = proj1t; tw.K[2] = 384;  tw.N[2] = 384;
    tw.src[3] = proj2_w; tw.dst[3] = proj2t; tw.K[3] = 384;  tw.N[3] = 384;
    tw.src[4] = m1f1w;   tw.dst[4] = fc11t;  tw.K[4] = 384;  tw.N[4] = 1536;
    tw.src[5] = m2f1w;   tw.dst[5] = fc12t;  tw.K[5] = 384;  tw.N[5] = 1536;
    tw.src[6] = m1f2w;   tw.dst[6] = fc21t;  tw.K[6] = 1536; tw.N[6] = 384;
    tw.src[7] = m2f2w;   tw.dst[7] = fc22t;  tw.K[7] = 1536; tw.N[7] = 384;
    transpose_w<<<dim3(48, 48, 8), dim3(256), 0, stream>>>(tw);

    // 2) LN over channels + transpose -> xn bf16 [R,384]
    ln_tr<<<dim3(32, 16, 2), dim3(256), 0, stream>>>(
        x1, x2, ln_a1_w, ln_a1_b, ln_a2_w, ln_a2_b, xn1, xn2);

    // 3) kqv = xn @ Wkqv; q pre-scaled; V scattered transposed into vt
    gemm128<0, 128><<<dim3(9, 128, 2), dim3(256), 0, stream>>>(
        xn1, xn2, kqv1t, kqv2t, (void*)kqv1, (void*)kqv2,
        (const float*)nullptr, (const float*)nullptr,
        (const void*)vt1, (const void*)vt2, 1152, 384);

    // 4) cross attention -> at (in d_out); XCD-co-located 1D grid
    attn_k<<<dim3(1536), dim3(256), 0, stream>>>(kqv1, kqv2, vt1, vt2, at1, at2);

    // 5) oa = x-residual + at @ proj + bias (f32; overlays dead kqv space)
    gemm128<1, 128><<<dim3(3, 128, 2), dim3(256), 0, stream>>>(
        at1, at2, proj1t, proj2t, (void*)oa1, (void*)oa2,
        proj1_b, proj2_b, (const void*)x1, (const void*)x2, 384, 384);

    // 6) h = LN(oa) -> xn buffers
    ln_rows<<<dim3(4096, 1, 2), dim3(256), 0, stream>>>(
        oa1, oa2, ln1_w, ln1_b, ln2_w, ln2_b, xn1, xn2);

    // 7) MLP in two M-halves; fc2 GEMM uses BN=64 tiles -> 768 blocks (3/CU)
    for (int half = 0; half < 2; ++half) {
        const size_t ro = (size_t)half * 8192;
        gemm128<2, 128><<<dim3(12, 64, 2), dim3(256), 0, stream>>>(
            xn1 + ro * 384, xn2 + ro * 384, fc11t, fc12t,
            (void*)hid_b1, (void*)hid_b2, m1f1b, m2f1b, nullptr, nullptr, 1536, 384);
        gemm128<3, 64><<<dim3(6, 64, 2), dim3(256), 0, stream>>>(
            hid_b1, hid_b2, fc21t, fc22t,
            (void*)(oa1 + ro * 384), (void*)(oa2 + ro * 384),
            m1f2b, m2f2b, (const void*)(oa1 + ro * 384), (const void*)(oa2 + ro * 384),
            384, 1536);
    }

    // 8) transpose back to [B, C, H, W] (f32, overwrites d_out)
    transpose_out<<<dim3(32, 12, 32), dim3(256), 0, stream>>>(oa1, oa2, (float*)d_out);
}

// Round 9
// 621.239 us; speedup vs baseline: 1.0226x; 1.0226x over previous
//
#include <hip/hip_runtime.h>
#include <math.h>

typedef unsigned short u16;
typedef __attribute__((ext_vector_type(8))) short short8;   // 8 x bf16 (4 VGPRs)
typedef __attribute__((ext_vector_type(4))) short short4b;  // 4 x bf16 (2 VGPRs)
typedef __attribute__((ext_vector_type(4))) float f32x4;

#define MFMA(a,b,c) __builtin_amdgcn_mfma_f32_16x16x32_bf16(a, b, c, 0, 0, 0)
// XOR-swizzled u16 offset of 16B chunk `ch` in row `row` (stride 64 u16)
#define SWZ(row, ch) ((((ch) ^ ((row) & 7)) << 3))
#define EXP2F(x) __builtin_amdgcn_exp2f(x)

// 16x16x16 bf16 MFMA (K=16): A-frag = 4 bf16, row=l&15, k=(l>>4)*4+j.
static __device__ __forceinline__ f32x4 MFMA16(short4b a, short4b b, f32x4 c) {
#if __has_builtin(__builtin_amdgcn_mfma_f32_16x16x16bf16_1k)
    return __builtin_amdgcn_mfma_f32_16x16x16bf16_1k(a, b, c, 0, 0, 0);
#else
    f32x4 d;
    asm volatile("v_mfma_f32_16x16x16_bf16 %0, %1, %2, %3\n\ts_nop 7"
                 : "=v"(d) : "v"(a), "v"(b), "v"(c));
    return d;
#endif
}

__device__ __forceinline__ float b2f(u16 v) {
    union { unsigned int i; float f; } c; c.i = ((unsigned int)v) << 16; return c.f;
}
__device__ __forceinline__ u16 f2b(float f) {   // RNE f32->bf16 (finite inputs only)
    union { float f; unsigned int i; } c; c.f = f;
    unsigned int u = c.i;
    return (u16)((u + 0x7fffu + ((u >> 16) & 1u)) >> 16);
}
__device__ __forceinline__ u16 f2b_p(float f) { // round-half-up, positive finite
    union { float f; unsigned int i; } c; c.f = f;
    return (u16)((c.i + 0x8000u) >> 16);
}

// Fast exact-GELU: erf via Abramowitz-Stegun 7.1.26 (|eps| <= 1.5e-7).
__device__ __forceinline__ float gelu_fast(float v) {
    float az = fabsf(v) * 0.70710678118f;               // |v|/sqrt(2)
    float t  = __builtin_amdgcn_rcpf(1.0f + 0.3275911f * az);
    float poly = ((((1.061405429f * t - 1.453152027f) * t + 1.421413741f) * t
                   - 0.284496736f) * t + 0.254829592f) * t;
    float e = EXP2F(az * az * -1.4426950408889634f);    // exp(-az^2)
    float erfv = 1.0f - poly * e;
    erfv = v >= 0.f ? erfv : -erfv;                     // erf is odd
    return 0.5f * v * (1.0f + erfv);
}

// ---------------------------------------------------------------------------
// Fused preprocessing: one launch carries BOTH independent jobs (they used
// to be two serialized launches on the stream):
//   z in [0,8): batched weight transpose  src [K][N] f32 -> dst [N][K] bf16
//   z in [8,10): LN over channel dim with transpose -> xn bf16 [R,384]
// Shared-memory union: max(32*33*4, 32*385*4 + 64*4) = 49536 B.
// ---------------------------------------------------------------------------
struct PrepArgs {
    const float* src[8]; u16* dst[8]; int K[8]; int N[8];
    const float* x0; const float* x1;
    const float* w0; const float* b0; const float* w1; const float* b1;
    u16* xn0; u16* xn1;
};

__global__ __launch_bounds__(256) void prep(PrepArgs a) {
    __shared__ alignas(16) char smem[49536];
    const int z = blockIdx.z;
    const int tid = threadIdx.x;
    if (z < 8) {
        // ---- transpose_w ----
        int K = a.K[z], N = a.N[z];
        int n0 = blockIdx.x * 32, k0 = blockIdx.y * 32;
        if (n0 >= N || k0 >= K) return;
        float (*t)[33] = (float(*)[33])smem;
        const float* s = a.src[z]; u16* d = a.dst[z];
        int tx = tid & 31, ty = tid >> 5;   // 32 x 8
        for (int i = 0; i < 32; i += 8)
            t[ty + i][tx] = s[(size_t)(k0 + ty + i) * N + n0 + tx];
        __syncthreads();
        for (int i = 0; i < 32; i += 8)
            d[(size_t)(n0 + ty + i) * K + k0 + tx] = f2b(t[tx][ty + i]);
    } else {
        // ---- ln_tr ----
        if (blockIdx.x >= 32 || blockIdx.y >= 16) return;
        int br = z - 8;
        const float* x  = br ? a.x1 : a.x0;
        const float* wv = br ? a.w1 : a.w0;
        const float* bv = br ? a.b1 : a.b0;
        u16* xn = br ? a.xn1 : a.xn0;
        int b = blockIdx.y, n0 = blockIdx.x * 32;
        float (*tile)[385] = (float(*)[385])smem;
        float* smu = (float*)(smem + 32 * 385 * 4);
        float* srs = smu + 32;
        const float* xb = x + (size_t)b * 384 * 1024 + n0;
        for (int idx = tid; idx < 384 * 8; idx += 256) {
            int c = idx >> 3, q = idx & 7;
            const float4 v = *(const float4*)&xb[(size_t)c * 1024 + q * 4];
            tile[q * 4 + 0][c] = v.x; tile[q * 4 + 1][c] = v.y;
            tile[q * 4 + 2][c] = v.z; tile[q * 4 + 3][c] = v.w;
        }
        __syncthreads();
        {
            int nn = tid >> 3, part = tid & 7;
            float s1 = 0.f, s2 = 0.f;
            for (int c = part * 48; c < part * 48 + 48; ++c) {
                float v = tile[nn][c]; s1 += v; s2 += v * v;
            }
            for (int off = 1; off < 8; off <<= 1) {
                s1 += __shfl_xor(s1, off, 64); s2 += __shfl_xor(s2, off, 64);
            }
            if (part == 0) {
                float mu = s1 * (1.f / 384.f);
                float var = s2 * (1.f / 384.f) - mu * mu;
                smu[nn] = mu; srs[nn] = rsqrtf(fmaxf(var, 0.f) + 1e-5f);
            }
        }
        __syncthreads();
        size_t rowbase = (size_t)b * 1024 + n0;
        for (int idx = tid; idx < 1536; idx += 256) {
            int nn = idx / 48, c0 = (idx - nn * 48) * 8;
            float mu = smu[nn], rs = srs[nn];
            u16 ov[8];
            #pragma unroll
            for (int k = 0; k < 8; k++) {
                int c = c0 + k;
                ov[k] = f2b((tile[nn][c] - mu) * rs * wv[c] + bv[c]);
            }
            *(uint4*)&xn[(rowbase + nn) * 384 + c0] = *(uint4*)ov;
        }
    }
}

// ---------------------------------------------------------------------------
// Row LayerNorm: in f32 [R,384] -> out bf16 [R,384]; one wave per row
// ---------------------------------------------------------------------------
__global__ __launch_bounds__(256)
void ln_rows(const float* __restrict__ i0, const float* __restrict__ i1,
             const float* __restrict__ w0, const float* __restrict__ bb0,
             const float* __restrict__ w1, const float* __restrict__ bb1,
             u16* __restrict__ o0, u16* __restrict__ o1) {
    int br = blockIdx.z;
    const float* in = br ? i1 : i0;
    const float* wv = br ? w1 : w0;
    const float* bv = br ? bb1 : bb0;
    u16* out = br ? o1 : o0;
    int w = threadIdx.x >> 6, l = threadIdx.x & 63;
    size_t row = (size_t)blockIdx.x * 4 + w;
    const float* p = in + row * 384;
    float v[6]; float s1 = 0.f, s2 = 0.f;
    #pragma unroll
    for (int j = 0; j < 6; j++) { v[j] = p[j * 64 + l]; s1 += v[j]; s2 += v[j] * v[j]; }
    for (int off = 1; off < 64; off <<= 1) {
        s1 += __shfl_xor(s1, off, 64); s2 += __shfl_xor(s2, off, 64);
    }
    float mu = s1 * (1.f / 384.f);
    float var = s2 * (1.f / 384.f) - mu * mu;
    float rs = rsqrtf(fmaxf(var, 0.f) + 1e-5f);
    #pragma unroll
    for (int j = 0; j < 6; j++) {
        int c = j * 64 + l;
        out[row * 384 + c] = f2b((v[j] - mu) * rs * wv[c] + bv[c]);
    }
}

// ---------------------------------------------------------------------------
// GEMM (round-3 configuration — best measured total, 623.5 us):
// C[M,N] = A[M,K] (row-major bf16) x Bt[N,K] (row-major bf16)
// 128x128 tile, BK=32, padded LDS (40), register-staged double buffer,
// 2-deep register prefetch, ONE barrier per K-step. 4 waves (2x2), 64x64 each.
// EPI: 0 = kqv epilogue (q pre-scale + V transpose-scatter), 1 = f32
// +bias+x-residual, 2 = bf16 gelu_fast(acc+bias), 3 = f32 +bias+residual.
// ---------------------------------------------------------------------------
template <int EPI>
__global__ __launch_bounds__(256)
void gemm128(const u16* __restrict__ A0, const u16* __restrict__ A1,
             const u16* __restrict__ B0, const u16* __restrict__ B1,
             void* C0v, void* C1v,
             const float* __restrict__ bias0, const float* __restrict__ bias1,
             const void* R0v, const void* R1v,
             int N, int K) {
    const int br = blockIdx.z;
    const u16* A = br ? A1 : A0;
    const u16* B = br ? B1 : B0;
    void* Cv = br ? C1v : C0v;
    const float* bias = br ? bias1 : bias0;
    const void* Rv = br ? R1v : R0v;

    const int n0 = blockIdx.x * 128;
    const int m0 = blockIdx.y * 128;
    const int tid = threadIdx.x;
    const int w = tid >> 6, l = tid & 63;
    const int wm = w >> 1, wn = w & 1;
    const int lr = l & 15, lq = l >> 4;

    __shared__ alignas(16) u16 As[2][128 * 40];   // pad 32->40 (bank spread)
    __shared__ alignas(16) u16 Bs[2][128 * 40];

    f32x4 acc[4][4];
    #pragma unroll
    for (int i = 0; i < 4; i++)
        #pragma unroll
        for (int j = 0; j < 4; j++) acc[i][j] = (f32x4)0.0f;

    const int ar0 = tid >> 2, ac0 = (tid & 3) * 8;
    const int ar1 = ar0 + 64;
    const u16* Ap0 = A + (size_t)(m0 + ar0) * K + ac0;
    const u16* Ap1 = A + (size_t)(m0 + ar1) * K + ac0;
    const u16* Bp0 = B + (size_t)(n0 + ar0) * K + ac0;
    const u16* Bp1 = B + (size_t)(n0 + ar1) * K + ac0;

    const int nk = K >> 5;
    uint4 pa0 = *(const uint4*)Ap0, pa1 = *(const uint4*)Ap1;
    uint4 pb0 = *(const uint4*)Bp0, pb1 = *(const uint4*)Bp1;
    *(uint4*)&As[0][ar0 * 40 + ac0] = pa0;
    *(uint4*)&As[0][ar1 * 40 + ac0] = pa1;
    *(uint4*)&Bs[0][ar0 * 40 + ac0] = pb0;
    *(uint4*)&Bs[0][ar1 * 40 + ac0] = pb1;
    pa0 = *(const uint4*)(Ap0 + 32); pa1 = *(const uint4*)(Ap1 + 32);
    pb0 = *(const uint4*)(Bp0 + 32); pb1 = *(const uint4*)(Bp1 + 32);
    __syncthreads();

    for (int kt = 0; kt < nk; ++kt) {
        const int cur = kt & 1;
        if (kt + 1 < nk) {      // stage regs (g[kt+1]) into other buffer
            const int nx = cur ^ 1;
            *(uint4*)&As[nx][ar0 * 40 + ac0] = pa0;
            *(uint4*)&As[nx][ar1 * 40 + ac0] = pa1;
            *(uint4*)&Bs[nx][ar0 * 40 + ac0] = pb0;
            *(uint4*)&Bs[nx][ar1 * 40 + ac0] = pb1;
        }
        if (kt + 2 < nk) {      // prefetch g[kt+2]
            const int kb = (kt + 2) * 32;
            pa0 = *(const uint4*)(Ap0 + kb); pa1 = *(const uint4*)(Ap1 + kb);
            pb0 = *(const uint4*)(Bp0 + kb); pb1 = *(const uint4*)(Bp1 + kb);
        }
        short8 af[4], bf[4];
        #pragma unroll
        for (int mt = 0; mt < 4; ++mt)
            af[mt] = *(const short8*)&As[cur][(wm * 64 + mt * 16 + lr) * 40 + lq * 8];
        #pragma unroll
        for (int nt = 0; nt < 4; ++nt)
            bf[nt] = *(const short8*)&Bs[cur][(wn * 64 + nt * 16 + lr) * 40 + lq * 8];
        #pragma unroll
        for (int mt = 0; mt < 4; ++mt)
            #pragma unroll
            for (int nt = 0; nt < 4; ++nt)
                acc[mt][nt] = MFMA(af[mt], bf[nt], acc[mt][nt]);
        __syncthreads();
    }

    #pragma unroll
    for (int mt = 0; mt < 4; ++mt)
        #pragma unroll
        for (int nt = 0; nt < 4; ++nt) {
            const int col = n0 + wn * 64 + nt * 16 + lr;
            const int rbase = m0 + wm * 64 + mt * 16 + lq * 4;
            const float bv = (EPI == 0) ? 0.f : bias[col];
            #pragma unroll
            for (int r = 0; r < 4; r++) {
                const int row = rbase + r;
                const size_t idx = (size_t)row * N + col;
                float v = acc[mt][nt][r];
                if (EPI == 0) {
                    if (col < 768) {
                        // q pre-scaled by 0.125*log2(e) for exp2-softmax
                        ((u16*)Cv)[idx] = f2b(col >= 384 ? v * 0.18033688f : v);
                    } else {    // V -> transposed vt[b][h][hd][n]
                        u16* vtb = (u16*)Rv;
                        vtb[((((size_t)(row >> 10)) * 6 + ((col - 768) >> 6)) * 64
                             + (col & 63)) * 1024 + (row & 1023)] = f2b(v);
                    }
                } else if (EPI == 1) {
                    float xr = ((const float*)Rv)[
                        ((size_t)(row >> 10) * 384 + col) * 1024 + (row & 1023)];
                    ((float*)Cv)[idx] = v + bv + xr;
                } else if (EPI == 2) {
                    ((u16*)Cv)[idx] = f2b(gelu_fast(v + bv));
                } else {
                    ((float*)Cv)[idx] = v + bv + ((const float*)Rv)[idx];
                }
            }
        }
}

// ---------------------------------------------------------------------------
// Cross flash-attention v6 (round-3 version — best measured, 139 us).
// Swapped QK^T (S^T = mfma(K,Q)): P stays in registers (16x16x16 PV);
// no Ps buffer; double-buffered K/V, one barrier per tile, setprio on MFMA.
// ---------------------------------------------------------------------------
__global__ __launch_bounds__(256)
void attn_k(const u16* __restrict__ kqvA, const u16* __restrict__ kqvB,
            const u16* __restrict__ vtA, const u16* __restrict__ vtB,
            u16* __restrict__ oA, u16* __restrict__ oB) {
    const int bid = blockIdx.x;
    const int g = bid & 7, qb = (bid >> 3) & 7, s = bid >> 6;
    const int grp = s * 8 + g;                  // 0..191
    const int ob = grp & 1, h = (grp >> 1) % 6, b = grp / 12;

    const u16* kqvQ  = (ob ? kqvB : kqvA) + (size_t)b * 1024 * 1152;
    const u16* kqvKV = (ob ? kqvA : kqvB) + (size_t)b * 1024 * 1152;
    const u16* vt    = (ob ? vtA : vtB) + ((size_t)b * 6 + h) * 64 * 1024;
    u16* outp = (ob ? oB : oA) + (size_t)b * 1024 * 384;
    const u16* qp = kqvQ + 384 + h * 64;
    const u16* kp = kqvKV + h * 64;

    __shared__ alignas(16) u16 Ks[2][64 * 64];
    __shared__ alignas(16) u16 Vts[2][64 * 64];   // V^T tile: [d][k]

    const int tid = threadIdx.x, w = tid >> 6, l = tid & 63;
    const int lr = l & 15, lq = l >> 4;

    // Q fragments in registers (loop-invariant, 16 VGPRs).
    short8 qf[2][2];
    #pragma unroll
    for (int a = 0; a < 2; a++)
        #pragma unroll
        for (int ks = 0; ks < 2; ks++)
            qf[a][ks] = *(const short8*)&qp[
                (size_t)(qb * 128 + w * 32 + a * 16 + lr) * 1152 + ks * 32 + lq * 8];

    const int srow = tid >> 3, sch = tid & 7;
    uint4 kpre[2][2], vpre[2][2];               // slot parity == tile parity
    #pragma unroll
    for (int t = 0; t < 2; t++)
        #pragma unroll
        for (int i = 0; i < 2; i++) {
            int row = srow + i * 32;
            kpre[t][i] = *(const uint4*)&kp[(size_t)(t * 64 + row) * 1152 + sch * 8];
            vpre[t][i] = *(const uint4*)&vt[(size_t)row * 1024 + t * 64 + sch * 8];
        }

    // prologue: stage tile 0 into buf 0; refill slot 0 <- tile 2
    #pragma unroll
    for (int i = 0; i < 2; i++) {
        int row = srow + i * 32;
        int o = row * 64 + SWZ(row, sch);
        *(uint4*)&Ks[0][o] = kpre[0][i];
        *(uint4*)&Vts[0][o] = vpre[0][i];
    }
    #pragma unroll
    for (int i = 0; i < 2; i++) {
        int row = srow + i * 32;
        kpre[0][i] = *(const uint4*)&kp[(size_t)(2 * 64 + row) * 1152 + sch * 8];
        vpre[0][i] = *(const uint4*)&vt[(size_t)row * 1024 + 2 * 64 + sch * 8];
    }

    f32x4 oacc[2][4];
    float psum[2] = {0.f, 0.f};
    #pragma unroll
    for (int a = 0; a < 2; a++)
        #pragma unroll
        for (int n = 0; n < 4; n++) oacc[a][n] = (f32x4)0.0f;

    __syncthreads();

    for (int jt = 0; jt < 16; ++jt) {
        const int cur = jt & 1, nx = cur ^ 1;
        if (jt + 1 < 16) {
            #pragma unroll
            for (int i = 0; i < 2; i++) {
                int row = srow + i * 32;
                int o = row * 64 + SWZ(row, sch);
                *(uint4*)&Ks[nx][o] = kpre[nx][i];
                *(uint4*)&Vts[nx][o] = vpre[nx][i];
            }
            if (jt + 3 < 16) {
                #pragma unroll
                for (int i = 0; i < 2; i++) {
                    int row = srow + i * 32;
                    kpre[nx][i] = *(const uint4*)&kp[(size_t)((jt + 3) * 64 + row) * 1152 + sch * 8];
                    vpre[nx][i] = *(const uint4*)&vt[(size_t)row * 1024 + (jt + 3) * 64 + sch * 8];
                }
            }
        }

        // S^T = K Q^T : sacc[kb][a], lane holds q=l&15 (col), k=kb*16+lq*4+r
        f32x4 sacc[4][2];
        #pragma unroll
        for (int kb = 0; kb < 4; kb++)
            #pragma unroll
            for (int a = 0; a < 2; a++) sacc[kb][a] = (f32x4)0.0f;
        __builtin_amdgcn_s_setprio(1);
        #pragma unroll
        for (int ks = 0; ks < 2; ++ks) {
            short8 bk[4];
            #pragma unroll
            for (int kb = 0; kb < 4; kb++) {
                int row = kb * 16 + lr;
                bk[kb] = *(const short8*)&Ks[cur][row * 64 + SWZ(row, ks * 4 + lq)];
            }
            #pragma unroll
            for (int kb = 0; kb < 4; kb++)
                #pragma unroll
                for (int a = 0; a < 2; a++)
                    sacc[kb][a] = MFMA(bk[kb], qf[a][ks], sacc[kb][a]);
        }
        __builtin_amdgcn_s_setprio(0);

        // P = exp2(S^T) entirely in registers: pack into 16x16x16 A-frags
        short4b ap16[2][4];
        #pragma unroll
        for (int a = 0; a < 2; a++)
            #pragma unroll
            for (int kb = 0; kb < 4; kb++) {
                f32x4 s4 = sacc[kb][a];
                float p0 = EXP2F(s4[0]), p1 = EXP2F(s4[1]);
                float p2 = EXP2F(s4[2]), p3 = EXP2F(s4[3]);
                psum[a] += (p0 + p1) + (p2 + p3);
                short4b pk;
                pk[0] = (short)f2b_p(p0); pk[1] = (short)f2b_p(p1);
                pk[2] = (short)f2b_p(p2); pk[3] = (short)f2b_p(p3);
                ap16[a][kb] = pk;
            }

        // O += P x V : PV via 16x16x16, B-frag = V^T[d = n*16+lr][k 4-contig]
        __builtin_amdgcn_s_setprio(1);
        #pragma unroll
        for (int kb = 0; kb < 4; ++kb) {
            short4b bv16[4];
            #pragma unroll
            for (int n = 0; n < 4; n++) {
                int row = n * 16 + lr;
                int addr = row * 64 + SWZ(row, kb * 2 + (lq >> 1)) + (lq & 1) * 4;
                bv16[n] = *(const short4b*)&Vts[cur][addr];
            }
            #pragma unroll
            for (int a = 0; a < 2; a++)
                #pragma unroll
                for (int n = 0; n < 4; n++)
                    oacc[a][n] = MFMA16(ap16[a][kb], bv16[n], oacc[a][n]);
        }
        __builtin_amdgcn_s_setprio(0);
        __syncthreads();   // tile jt+1 staged AND buf cur free for tile jt+2
    }

    #pragma unroll
    for (int a = 0; a < 2; a++) {
        psum[a] += __shfl_xor(psum[a], 16, 64);
        psum[a] += __shfl_xor(psum[a], 32, 64);
        psum[a] = 1.f / psum[a];
    }
    float rec[2][4];
    #pragma unroll
    for (int a = 0; a < 2; a++)
        #pragma unroll
        for (int r = 0; r < 4; r++)
            rec[a][r] = __shfl(psum[a], lq * 4 + r, 64);

    #pragma unroll
    for (int a = 0; a < 2; a++)
        #pragma unroll
        for (int n = 0; n < 4; n++)
            #pragma unroll
            for (int r = 0; r < 4; r++) {
                size_t row = (size_t)qb * 128 + w * 32 + a * 16 + lq * 4 + r;
                int col = h * 64 + n * 16 + lr;
                outp[row * 384 + col] = f2b(oacc[a][n][r] * rec[a][r]);
            }
}

// ---------------------------------------------------------------------------
// Final transpose: res f32 [R,384] -> d_out FLOAT32 [2][16][384][1024]
// ---------------------------------------------------------------------------
__global__ __launch_bounds__(256)
void transpose_out(const float* __restrict__ r0, const float* __restrict__ r1,
                   float* __restrict__ out) {
    int z = blockIdx.z, ob = z >> 4, b = z & 15;
    const float* rp = ob ? r1 : r0;
    int c0 = blockIdx.y * 32, n0 = blockIdx.x * 32;
    __shared__ float t[32][33];
    int tx = threadIdx.x & 31, ty = threadIdx.x >> 5;
    for (int i = 0; i < 32; i += 8)
        t[ty + i][tx] = rp[((size_t)b * 1024 + n0 + ty + i) * 384 + c0 + tx];
    __syncthreads();
    for (int i = 0; i < 32; i += 8)
        out[(size_t)ob * 6291456 + ((size_t)b * 384 + c0 + ty + i) * 1024 + n0 + tx]
            = t[tx][ty + i];
}

// ---------------------------------------------------------------------------
extern "C" void kernel_launch(void* const* d_in, const int* in_sizes, int n_in,
                              void* d_out, int out_size, void* d_ws, size_t ws_size,
                              hipStream_t stream) {
    const float* x1      = (const float*)d_in[0];
    const float* x2      = (const float*)d_in[1];
    const float* ln_a1_w = (const float*)d_in[2];
    const float* ln_a1_b = (const float*)d_in[3];
    const float* kqv1_w  = (const float*)d_in[4];
    const float* ln_a2_w = (const float*)d_in[5];
    const float* ln_a2_b = (const float*)d_in[6];
    const float* kqv2_w  = (const float*)d_in[7];
    const float* proj1_w = (const float*)d_in[8];
    const float* proj1_b = (const float*)d_in[9];
    const float* proj2_w = (const float*)d_in[10];
    const float* proj2_b = (const float*)d_in[11];
    const float* ln1_w   = (const float*)d_in[12];
    const float* ln1_b   = (const float*)d_in[13];
    const float* ln2_w   = (const float*)d_in[14];
    const float* ln2_b   = (const float*)d_in[15];
    const float* m1f1w   = (const float*)d_in[16];
    const float* m1f1b   = (const float*)d_in[17];
    const float* m1f2w   = (const float*)d_in[18];
    const float* m1f2b   = (const float*)d_in[19];
    const float* m2f1w   = (const float*)d_in[20];
    const float* m2f1b   = (const float*)d_in[21];
    const float* m2f2w   = (const float*)d_in[22];
    const float* m2f2b   = (const float*)d_in[23];
    (void)in_sizes; (void)n_in; (void)out_size; (void)ws_size;

    const size_t R = 16384;
    char* ws = (char*)d_ws;
    size_t off = 0;
    auto alloc = [&](size_t bytes) -> char* {
        char* p = ws + off;
        off = (off + bytes + 255) & ~(size_t)255;
        return p;
    };
    // --- weights (persistent, 7.08 MB) ---
    u16* kqv1t  = (u16*)alloc(1152 * 384 * 2);
    u16* kqv2t  = (u16*)alloc(1152 * 384 * 2);
    u16* proj1t = (u16*)alloc(384 * 384 * 2);
    u16* proj2t = (u16*)alloc(384 * 384 * 2);
    u16* fc11t  = (u16*)alloc(1536 * 384 * 2);
    u16* fc12t  = (u16*)alloc(1536 * 384 * 2);
    u16* fc21t  = (u16*)alloc(384 * 1536 * 2);
    u16* fc22t  = (u16*)alloc(384 * 1536 * 2);
    // --- REGION_B: xn (bf16 [R,384] x2), later h ---
    u16* xn1 = (u16*)alloc(R * 384 * 2);
    u16* xn2 = (u16*)alloc(R * 384 * 2);
    // --- REGION_C: kqv (bf16 [R,1152] x2); later oa (f32 x2) + hid_b2 ---
    char* regC = alloc(R * 1152 * 2 * 2);
    u16* kqv1 = (u16*)regC;
    u16* kqv2 = (u16*)(regC + R * 1152 * 2);
    float* oa1 = (float*)regC;
    float* oa2 = (float*)(regC + R * 384 * 4);
    u16* hid_b2 = (u16*)(regC + 2 * R * 384 * 4);
    // d_out (50.33 MB) scratch: at (25.17) + vt1/vt2 (12.58 each); exact fit
    u16* at1 = (u16*)d_out;
    u16* at2 = at1 + R * 384;
    u16* vt1 = at2 + R * 384;                   // [16][6][64][1024] bf16
    u16* vt2 = vt1 + (size_t)16 * 6 * 64 * 1024;
    u16* hid_b1 = (u16*)d_out;                  // later: bf16 [R/2,1536]

    // 1) fused preprocessing: weight transposes (z<8) + channel-LN (z=8,9)
    PrepArgs pa;
    pa.src[0] = kqv1_w;  pa.dst[0] = kqv1t;  pa.K[0] = 384;  pa.N[0] = 1152;
    pa.src[1] = kqv2_w;  pa.dst[1] = kqv2t;  pa.K[1] = 384;  pa.N[1] = 1152;
    pa.src[2] = proj1_w; pa.dst[2] = proj1t; pa.K[2] = 384;  pa.N[2] = 384;
    pa.src[3] = proj2_w; pa.dst[3] = proj2t; pa.K[3] = 384;  pa.N[3] = 384;
    pa.src[4] = m1f1w;   pa.dst[4] = fc11t;  pa.K[4] = 384;  pa.N[4] = 1536;
    pa.src[5] = m2f1w;   pa.dst[5] = fc12t;  pa.K[5] = 384;  pa.N[5] = 1536;
    pa.src[6] = m1f2w;   pa.dst[6] = fc21t;  pa.K[6] = 1536; pa.N[6] = 384;
    pa.src[7] = m2f2w;   pa.dst[7] = fc22t;  pa.K[7] = 1536; pa.N[7] = 384;
    pa.x0 = x1; pa.x1 = x2;
    pa.w0 = ln_a1_w; pa.b0 = ln_a1_b; pa.w1 = ln_a2_w; pa.b1 = ln_a2_b;
    pa.xn0 = xn1; pa.xn1 = xn2;
    prep<<<dim3(48, 48, 10), dim3(256), 0, stream>>>(pa);

    // 2) kqv = xn @ Wkqv; q pre-scaled; V scattered transposed into vt
    gemm128<0><<<dim3(9, 128, 2), dim3(256), 0, stream>>>(
        xn1, xn2, kqv1t, kqv2t, (void*)kqv1, (void*)kqv2,
        (const float*)nullptr, (const float*)nullptr,
        (const void*)vt1, (const void*)vt2, 1152, 384);

    // 3) cross attention -> at (in d_out); XCD-co-located 1D grid
    attn_k<<<dim3(1536), dim3(256), 0, stream>>>(kqv1, kqv2, vt1, vt2, at1, at2);

    // 4) oa = x-residual + at @ proj + bias (f32; overlays dead kqv space)
    gemm128<1><<<dim3(3, 128, 2), dim3(256), 0, stream>>>(
        at1, at2, proj1t, proj2t, (void*)oa1, (void*)oa2,
        proj1_b, proj2_b, (const void*)x1, (const void*)x2, 384, 384);

    // 5) h = LN(oa) -> xn buffers
    ln_rows<<<dim3(4096, 1, 2), dim3(256), 0, stream>>>(
        oa1, oa2, ln1_w, ln1_b, ln2_w, ln2_b, xn1, xn2);

    // 6) MLP in two M-halves
    for (int half = 0; half < 2; ++half) {
        const size_t ro = (size_t)half * 8192;
        gemm128<2><<<dim3(12, 64, 2), dim3(256), 0, stream>>>(
            xn1 + ro * 384, xn2 + ro * 384, fc11t, fc12t,
            (void*)hid_b1, (void*)hid_b2, m1f1b, m2f1b, nullptr, nullptr, 1536, 384);
        gemm128<3><<<dim3(3, 64, 2), dim3(256), 0, stream>>>(
            hid_b1, hid_b2, fc21t, fc22t,
            (void*)(oa1 + ro * 384), (void*)(oa2 + ro * 384),
            m1f2b, m2f2b, (const void*)(oa1 + ro * 384), (const void*)(oa2 + ro * 384),
            384, 1536);
    }

    // 7) transpose back to [B, C, H, W] (f32, overwrites d_out)
    transpose_out<<<dim3(32, 12, 32), dim3(256), 0, stream>>>(oa1, oa2, (float*)d_out);
}